// Round 3
// baseline (3436.909 us; speedup 1.0000x reference)
//
#include <hip/hip_runtime.h>

// x: [T=8, B=16, Cin=64, H=64, W=64] fp32
// W: [Cout=128, Cin=64, 3, 3] fp32
// out: spikes [T, B, Cout, H, W] fp32 (0.0 / 1.0)
//
// Precision: output is Heaviside(v-1) vs a precision-neutral (fp64) numpy
// reference; all conv accumulation + LIF state must be fp64 (R2: absmax 0.0).
//
// R3: weights pre-converted to fp64 in d_ws with [ci][k][co] layout (no cvt
// in hot loop, contiguous dwordx4 loads); x LDS staged in 2 ci-chunks of 32
// (27.6 KB) to raise occupancy 8 -> 12 waves/CU.
#define TT 8
#define BB 16
#define CIN 64
#define COUT 128
#define HH 64
#define WW 64

#define TILE_H 4
#define TILE_W 16
#define XS_H (TILE_H + 2)                 // 6
#define XS_W (TILE_W + 2)                 // 18
#define XS_ROW (XS_H * XS_W)              // 108 doubles per ci
#define CI_CHUNK 32
#define XS_N (CI_CHUNK * XS_ROW)          // 3456 doubles = 27.6 KB

#define W_ELEMS (CIN * 9 * COUT)          // 73728
#define W_BYTES (W_ELEMS * 8)             // 589824

// ---- prologue: W [co][ci][k] fp32 -> ws [ci][k][co] fp64 ----
__global__ void wconv_f64(const float* __restrict__ Wt, double* __restrict__ wd) {
    int idx = blockIdx.x * 256 + threadIdx.x;   // idx = (ci*9 + k)*128 + co
    if (idx >= W_ELEMS) return;
    int co = idx & 127;
    int cik = idx >> 7;         // ci*9 + k
    int ci = cik / 9;
    int k = cik - ci * 9;
    wd[idx] = (double)Wt[((size_t)co * CIN + ci) * 9 + k];
}

// Block: 256 threads = 16 cout-groups (8 co each) x 16 pixel columns.
// Each thread: 8 co x 4 rows = 32 outputs; v[32] (double) in regs across t.
// Grid: (64/16=4, 64/4=16, B=16) = 1024 blocks.
__global__ __launch_bounds__(256, 3)
void convlif_f64w(const float* __restrict__ x, const double* __restrict__ wd,
                  float* __restrict__ out) {
    __shared__ double xs[XS_N];

    const int tid = threadIdx.x;
    const int pt = tid & 15;        // pixel column 0..15
    const int cg = tid >> 4;        // cout group 0..15
    const int w0 = blockIdx.x * TILE_W;
    const int h0 = blockIdx.y * TILE_H;
    const int b = blockIdx.z;
    const int co_base = cg * 8;

    double v[32];
#pragma unroll
    for (int i = 0; i < 32; ++i) v[i] = 0.0;

    for (int t = 0; t < TT; ++t) {
        const float* xb = x + (size_t)(t * BB + b) * (CIN * HH * WW);
        double acc[32];
#pragma unroll
        for (int i = 0; i < 32; ++i) acc[i] = 0.0;

        for (int cc = 0; cc < CIN; cc += CI_CHUNK) {
            __syncthreads();  // protect xs from previous chunk's readers
            for (int idx = tid; idx < XS_N; idx += 256) {
                int cil = idx / XS_ROW;
                int rem = idx - cil * XS_ROW;
                int hh = rem / XS_W;
                int ww2 = rem - hh * XS_W;
                int gh = h0 - 1 + hh;
                int gw = w0 - 1 + ww2;
                double val = 0.0;
                if (gh >= 0 && gh < HH && gw >= 0 && gw < WW)
                    val = (double)xb[(cc + cil) * (HH * WW) + gh * WW + gw];
                xs[idx] = val;
            }
            __syncthreads();

            for (int cil = 0; cil < CI_CHUNK; ++cil) {
                const double* xr = xs + cil * XS_ROW;
                const double* wrow = wd + (size_t)((cc + cil) * 9) * COUT + co_base;
#pragma unroll
                for (int k = 0; k < 9; ++k) {
                    const int kh = k / 3, kw = k - kh * 3;
                    const double2* wp = (const double2*)(wrow + k * COUT);
                    double2 w01 = wp[0], w23 = wp[1], w45 = wp[2], w67 = wp[3];
                    double wv[8] = {w01.x, w01.y, w23.x, w23.y,
                                    w45.x, w45.y, w67.x, w67.y};
                    double xv[4];
#pragma unroll
                    for (int j = 0; j < 4; ++j)
                        xv[j] = xr[(j + kh) * XS_W + pt + kw];
#pragma unroll
                    for (int i = 0; i < 8; ++i) {
#pragma unroll
                        for (int j = 0; j < 4; ++j)
                            acc[i * 4 + j] = fma(wv[i], xv[j], acc[i * 4 + j]);
                    }
                }
            }
        }

        // ---- LIF update + spike store (exact *0.5) ----
        float* ob = out + (size_t)(t * BB + b) * (COUT * HH * WW);
#pragma unroll
        for (int i = 0; i < 8; ++i) {
#pragma unroll
            for (int j = 0; j < 4; ++j) {
                int k = i * 4 + j;
                double vv = v[k] + (acc[k] - v[k]) * 0.5;  // v += (z - v)/tau
                bool s = (vv >= 1.0);
                ob[(size_t)(co_base + i) * (HH * WW) + (h0 + j) * WW + (w0 + pt)]
                    = s ? 1.0f : 0.0f;
                v[k] = s ? 0.0 : vv;
            }
        }
    }
}

// ---- fallback (R2 kernel): in-loop weight convert, no d_ws needed ----
#define FXS_H 6
#define FXS_W 18
#define FXS_ROW (FXS_H * FXS_W)
#define FXS_N (CIN * FXS_ROW)
__global__ __launch_bounds__(256, 2)
void convlif_f64(const float* __restrict__ x, const float* __restrict__ Wt,
                 float* __restrict__ out) {
    __shared__ double xs[FXS_N];
    const int tid = threadIdx.x;
    const int pt = tid & 15;
    const int cg = tid >> 4;
    const int w0 = blockIdx.x * TILE_W;
    const int h0 = blockIdx.y * TILE_H;
    const int b = blockIdx.z;
    const int co_base = cg * 8;
    double v[32];
#pragma unroll
    for (int i = 0; i < 32; ++i) v[i] = 0.0;
    for (int t = 0; t < TT; ++t) {
        __syncthreads();
        const float* xb = x + (size_t)(t * BB + b) * (CIN * HH * WW);
        for (int idx = tid; idx < FXS_N; idx += 256) {
            int ci = idx / FXS_ROW;
            int rem = idx - ci * FXS_ROW;
            int hh = rem / FXS_W;
            int ww2 = rem - hh * FXS_W;
            int gh = h0 - 1 + hh;
            int gw = w0 - 1 + ww2;
            double val = 0.0;
            if (gh >= 0 && gh < HH && gw >= 0 && gw < WW)
                val = (double)xb[ci * (HH * WW) + gh * WW + gw];
            xs[idx] = val;
        }
        __syncthreads();
        double acc[32];
#pragma unroll
        for (int i = 0; i < 32; ++i) acc[i] = 0.0;
        for (int ci = 0; ci < CIN; ++ci) {
            const float* wr = Wt + (size_t)co_base * (CIN * 9) + ci * 9;
            const double* xr = xs + ci * FXS_ROW;
#pragma unroll
            for (int kh = 0; kh < 3; ++kh) {
#pragma unroll
                for (int kw = 0; kw < 3; ++kw) {
                    double wv[8];
#pragma unroll
                    for (int i = 0; i < 8; ++i)
                        wv[i] = (double)wr[i * (CIN * 9) + kh * 3 + kw];
                    double xv[4];
#pragma unroll
                    for (int j = 0; j < 4; ++j)
                        xv[j] = xr[(j + kh) * FXS_W + pt + kw];
#pragma unroll
                    for (int i = 0; i < 8; ++i) {
#pragma unroll
                        for (int j = 0; j < 4; ++j)
                            acc[i * 4 + j] = fma(wv[i], xv[j], acc[i * 4 + j]);
                    }
                }
            }
        }
        float* ob = out + (size_t)(t * BB + b) * (COUT * HH * WW);
#pragma unroll
        for (int i = 0; i < 8; ++i) {
#pragma unroll
            for (int j = 0; j < 4; ++j) {
                int k = i * 4 + j;
                double vv = v[k] + (acc[k] - v[k]) * 0.5;
                bool s = (vv >= 1.0);
                ob[(size_t)(co_base + i) * (HH * WW) + (h0 + j) * WW + (w0 + pt)]
                    = s ? 1.0f : 0.0f;
                v[k] = s ? 0.0 : vv;
            }
        }
    }
}

extern "C" void kernel_launch(void* const* d_in, const int* in_sizes, int n_in,
                              void* d_out, int out_size, void* d_ws, size_t ws_size,
                              hipStream_t stream) {
    const float* x = (const float*)d_in[0];
    const float* Wt = (const float*)d_in[1];
    float* out = (float*)d_out;
    dim3 grid(WW / TILE_W, HH / TILE_H, BB);
    if (ws_size >= (size_t)W_BYTES) {
        double* wd = (double*)d_ws;
        wconv_f64<<<(W_ELEMS + 255) / 256, 256, 0, stream>>>(Wt, wd);
        convlif_f64w<<<grid, 256, 0, stream>>>(x, wd, out);
    } else {
        convlif_f64<<<grid, 256, 0, stream>>>(x, Wt, out);
    }
}

// Round 4
// 2559.179 us; speedup vs baseline: 1.3430x; 1.3430x over previous
//
#include <hip/hip_runtime.h>

// x: [T=8, B=16, Cin=64, H=64, W=64] fp32
// W: [Cout=128, Cin=64, 3, 3] fp32
// out: spikes [T, B, Cout, H, W] fp32 (0.0 / 1.0)
//
// Precision: output is Heaviside(v-1) vs precision-neutral (fp64) numpy ref;
// all conv accumulation + LIF state must be fp64 (R2: absmax 0.0).
//
// R4: two-phase. Phase 1: conv-only kernel (no LIF state in regs -> acc[32]
// only, ~100 VGPR, high occupancy) writes z fp64 to d_ws. Phase 2: LIF scan,
// memory-bound. R3 lesson: v[32]+acc[32] fused design needs >=128 regs; any
// launch_bounds beyond (256,2) spills to scratch (84 VGPR, +290 MB traffic).
#define TT 8
#define BB 16
#define CIN 64
#define COUT 128
#define HH 64
#define WW 64

#define TILE_H 4
#define TILE_W 16
#define XS_H (TILE_H + 2)                 // 6
#define XS_W (TILE_W + 2)                 // 18
#define XS_ROW (XS_H * XS_W)              // 108 floats per ci
#define XS_N (CIN * XS_ROW)               // 6912 floats = 27.6 KB

#define W_ELEMS (CIN * 9 * COUT)          // 73728
#define W_BYTES ((size_t)W_ELEMS * 8)     // 589824 (16B-aligned)
#define NPLANE (BB * COUT * HH * WW)      // 8388608 elems per t-plane
#define Z_BYTES ((size_t)TT * NPLANE * 8) // 536870912

// ---- prologue: W [co][ci][k] fp32 -> wd [ci][k][co] fp64 ----
__global__ void wconv_f64(const float* __restrict__ Wt, double* __restrict__ wd) {
    int idx = blockIdx.x * 256 + threadIdx.x;   // idx = (ci*9 + k)*128 + co
    if (idx >= W_ELEMS) return;
    int co = idx & 127;
    int cik = idx >> 7;
    int ci = cik / 9;
    int k = cik - ci * 9;
    wd[idx] = (double)Wt[((size_t)co * CIN + ci) * 9 + k];
}

// ---- phase 1: 3x3 conv, fp64 accumulate, z to workspace ----
// Block: 256 thr = 16 cout-groups (8 co) x 16 cols; thread: 8 co x 4 rows.
// Grid: (4, 16, T*B=128) = 8192 blocks.
__global__ __launch_bounds__(256, 2)
void conv_f64(const float* __restrict__ x, const double* __restrict__ wd,
              double* __restrict__ z) {
    __shared__ float xs[XS_N];

    const int tid = threadIdx.x;
    const int pt = tid & 15;
    const int cg = tid >> 4;
    const int w0 = blockIdx.x * TILE_W;
    const int h0 = blockIdx.y * TILE_H;
    const int tb = blockIdx.z;
    const int co_base = cg * 8;

    const float* xb = x + (size_t)tb * (CIN * HH * WW);
    for (int idx = tid; idx < XS_N; idx += 256) {
        int ci = idx / XS_ROW;
        int rem = idx - ci * XS_ROW;
        int hh = rem / XS_W;
        int ww2 = rem - hh * XS_W;
        int gh = h0 - 1 + hh;
        int gw = w0 - 1 + ww2;
        float val = 0.0f;
        if (gh >= 0 && gh < HH && gw >= 0 && gw < WW)
            val = xb[ci * (HH * WW) + gh * WW + gw];
        xs[idx] = val;
    }
    __syncthreads();

    double acc[32];
#pragma unroll
    for (int i = 0; i < 32; ++i) acc[i] = 0.0;

    for (int ci = 0; ci < CIN; ++ci) {
        const float* xr = xs + ci * XS_ROW;
        const double* wrow = wd + (size_t)(ci * 9) * COUT + co_base;
#pragma unroll
        for (int kh = 0; kh < 3; ++kh) {
#pragma unroll
            for (int kw = 0; kw < 3; ++kw) {
                const double2* wp = (const double2*)(wrow + (kh * 3 + kw) * COUT);
                double2 w01 = wp[0], w23 = wp[1], w45 = wp[2], w67 = wp[3];
                double wv[8] = {w01.x, w01.y, w23.x, w23.y,
                                w45.x, w45.y, w67.x, w67.y};
                double xv[4];
#pragma unroll
                for (int j = 0; j < 4; ++j)
                    xv[j] = (double)xr[(j + kh) * XS_W + pt + kw];
#pragma unroll
                for (int i = 0; i < 8; ++i) {
#pragma unroll
                    for (int j = 0; j < 4; ++j)
                        acc[i * 4 + j] = fma(wv[i], xv[j], acc[i * 4 + j]);
                }
            }
        }
    }

    double* zb = z + (size_t)tb * (COUT * HH * WW);
#pragma unroll
    for (int i = 0; i < 8; ++i) {
#pragma unroll
        for (int j = 0; j < 4; ++j)
            zb[(size_t)(co_base + i) * (HH * WW) + (h0 + j) * WW + (w0 + pt)]
                = acc[i * 4 + j];
    }
}

// ---- phase 2: LIF scan over t (memory-bound) ----
// Thread handles 2 consecutive positions; grid 8388608/2/256 = 16384 blocks.
__global__ __launch_bounds__(256)
void lif_scan(const double* __restrict__ z, float* __restrict__ out) {
    size_t n = ((size_t)blockIdx.x * 256 + threadIdx.x) * 2;
    double v0 = 0.0, v1 = 0.0;
#pragma unroll
    for (int t = 0; t < TT; ++t) {
        double2 zz = *(const double2*)(z + (size_t)t * NPLANE + n);
        v0 = v0 + (zz.x - v0) * 0.5;   // v += (z - v)/tau, tau=2 exact
        v1 = v1 + (zz.y - v1) * 0.5;
        bool s0 = (v0 >= 1.0), s1 = (v1 >= 1.0);
        float2 o;
        o.x = s0 ? 1.0f : 0.0f;
        o.y = s1 ? 1.0f : 0.0f;
        *(float2*)(out + (size_t)t * NPLANE + n) = o;
        v0 = s0 ? 0.0 : v0;
        v1 = s1 ? 0.0 : v1;
    }
}

// ---- fallback: R2 fused kernel (known-good 2271 us), if ws too small ----
#define FXS_H 6
#define FXS_W 18
#define FXS_ROW (FXS_H * FXS_W)
#define FXS_N (CIN * FXS_ROW)
__global__ __launch_bounds__(256, 2)
void convlif_f64(const float* __restrict__ x, const float* __restrict__ Wt,
                 float* __restrict__ out) {
    __shared__ double xs[FXS_N];
    const int tid = threadIdx.x;
    const int pt = tid & 15;
    const int cg = tid >> 4;
    const int w0 = blockIdx.x * TILE_W;
    const int h0 = blockIdx.y * TILE_H;
    const int b = blockIdx.z;
    const int co_base = cg * 8;
    double v[32];
#pragma unroll
    for (int i = 0; i < 32; ++i) v[i] = 0.0;
    for (int t = 0; t < TT; ++t) {
        __syncthreads();
        const float* xb = x + (size_t)(t * BB + b) * (CIN * HH * WW);
        for (int idx = tid; idx < FXS_N; idx += 256) {
            int ci = idx / FXS_ROW;
            int rem = idx - ci * FXS_ROW;
            int hh = rem / FXS_W;
            int ww2 = rem - hh * FXS_W;
            int gh = h0 - 1 + hh;
            int gw = w0 - 1 + ww2;
            double val = 0.0;
            if (gh >= 0 && gh < HH && gw >= 0 && gw < WW)
                val = (double)xb[ci * (HH * WW) + gh * WW + gw];
            xs[idx] = val;
        }
        __syncthreads();
        double acc[32];
#pragma unroll
        for (int i = 0; i < 32; ++i) acc[i] = 0.0;
        for (int ci = 0; ci < CIN; ++ci) {
            const float* wr = Wt + (size_t)co_base * (CIN * 9) + ci * 9;
            const double* xr = xs + ci * FXS_ROW;
#pragma unroll
            for (int kh = 0; kh < 3; ++kh) {
#pragma unroll
                for (int kw = 0; kw < 3; ++kw) {
                    double wv[8];
#pragma unroll
                    for (int i = 0; i < 8; ++i)
                        wv[i] = (double)wr[i * (CIN * 9) + kh * 3 + kw];
                    double xv[4];
#pragma unroll
                    for (int j = 0; j < 4; ++j)
                        xv[j] = xr[(j + kh) * FXS_W + pt + kw];
#pragma unroll
                    for (int i = 0; i < 8; ++i) {
#pragma unroll
                        for (int j = 0; j < 4; ++j)
                            acc[i * 4 + j] = fma(wv[i], xv[j], acc[i * 4 + j]);
                    }
                }
            }
        }
        float* ob = out + (size_t)(t * BB + b) * (COUT * HH * WW);
#pragma unroll
        for (int i = 0; i < 8; ++i) {
#pragma unroll
            for (int j = 0; j < 4; ++j) {
                int k = i * 4 + j;
                double vv = v[k] + (acc[k] - v[k]) * 0.5;
                bool s = (vv >= 1.0);
                ob[(size_t)(co_base + i) * (HH * WW) + (h0 + j) * WW + (w0 + pt)]
                    = s ? 1.0f : 0.0f;
                v[k] = s ? 0.0 : vv;
            }
        }
    }
}

extern "C" void kernel_launch(void* const* d_in, const int* in_sizes, int n_in,
                              void* d_out, int out_size, void* d_ws, size_t ws_size,
                              hipStream_t stream) {
    const float* x = (const float*)d_in[0];
    const float* Wt = (const float*)d_in[1];
    float* out = (float*)d_out;
    if (ws_size >= W_BYTES + Z_BYTES) {
        double* wd = (double*)d_ws;
        double* z = (double*)((char*)d_ws + W_BYTES);
        wconv_f64<<<(W_ELEMS + 255) / 256, 256, 0, stream>>>(Wt, wd);
        dim3 cgrid(WW / TILE_W, HH / TILE_H, TT * BB);
        conv_f64<<<cgrid, 256, 0, stream>>>(x, wd, z);
        lif_scan<<<NPLANE / 2 / 256, 256, 0, stream>>>(z, out);
    } else {
        dim3 grid(WW / TILE_W, HH / TILE_H, BB);
        convlif_f64<<<grid, 256, 0, stream>>>(x, Wt, out);
    }
}

// Round 6
// 2106.947 us; speedup vs baseline: 1.6312x; 1.2146x over previous
//
#include <hip/hip_runtime.h>
#include <math.h>

// x: [T=8, B=16, Cin=64, H=64, W=64] fp32
// W: [Cout=128, Cin=64, 3, 3] fp32
// out: spikes [T, B, Cout, H, W] fp32 (0.0 / 1.0)
//
// Precision: output is Heaviside(v-1) vs precision-neutral (fp64) numpy ref;
// all conv accumulation + LIF state must be fp64 (R2: absmax 0.0).
//
// R6: R5's f64-MFMA conv failed; index audit clean => the unverified part is
// the v_mfma_f64_16x16x4_f64 fragment layout. This round self-probes the D
// layout at runtime (4 candidates) and selects the store mapping; if none
// match, falls back to the trusted vector-fp64 conv (R4). Pass guaranteed;
// timing reveals which path ran.
#define TT 8
#define BB 16
#define CIN 64
#define COUT 128
#define HH 64
#define WW 64

#define PW 16
#define PH 8
#define XS_W2 (PW + 2)                     // 18
#define XS_H2 (PH + 2)                     // 10
#define CI_CHUNK 16
#define XS_ROW (XS_H2 * XS_W2)             // 180 doubles per ci
#define XS_N (CI_CHUNK * XS_ROW)           // 2880 doubles = 23 KB

#define W_ELEMS (CIN * 9 * COUT)           // 73728
#define W_BYTES ((size_t)W_ELEMS * 8)      // 589824
#define NPLANE (BB * COUT * HH * WW)       // 8388608 per t-plane
#define Z_BYTES ((size_t)TT * NPLANE * 8)  // 512 MB
#define FLAG_OFF (W_BYTES + Z_BYTES)
#define WS_NEED (FLAG_OFF + 16)

typedef double d4 __attribute__((ext_vector_type(4)));

// ---- prologue: W [co][ci][kh][kw] fp32 -> wd [k=(ci,kh,kw)][co] fp64 ----
__global__ void wconv_f64(const float* __restrict__ Wt, double* __restrict__ wd) {
    int idx = blockIdx.x * 256 + threadIdx.x;
    if (idx >= W_ELEMS) return;
    int co = idx & 127;
    int k = idx >> 7;
    int ci = k / 9;
    int r = k - ci * 9;
    wd[idx] = (double)Wt[((size_t)co * CIN + ci) * 9 + r];
}

// ---- probe: discover f64 MFMA D layout on this hardware ----
// Assumed input layouts (only sensible ones dim-wise): A[m][k]: m=lane&15,
// k=lane>>4; B[k][n]: n=lane&15, k=lane>>4. src0/src1-swap semantics are
// equivalent to a D transpose, so 4 D candidates cover swap cases too.
__global__ void mfma_probe(int* __restrict__ flag) {
    int lane = threadIdx.x;
    int l15 = lane & 15, q = lane >> 4;
    double a = (double)(l15 * 4 + q + 1);             // A[m][k] = m*4+k+1
    double b = (double)(q * 16 + l15 + 1) * 0.001;    // B[k][n] = (k*16+n+1)/1000
    d4 acc = (d4)(0.0);
    acc = __builtin_amdgcn_mfma_f64_16x16x4f64(a, b, acc, 0, 0, 0);
    bool ok0 = true, ok1 = true, ok2 = true, ok3 = true;
    for (int d = 0; d < 4; ++d) {
        double e0 = 0, e1 = 0, e2 = 0, e3 = 0;
        for (int k = 0; k < 4; ++k) {
            // V0: D[4q+d][l15]   V1: D[l15][4q+d]
            e0 += (double)((4 * q + d) * 4 + k + 1) * ((double)(k * 16 + l15 + 1) * 0.001);
            e1 += (double)(l15 * 4 + k + 1) * ((double)(k * 16 + 4 * q + d + 1) * 0.001);
            // V2: D[q+4d][l15]   V3: D[l15][q+4d]
            e2 += (double)((q + 4 * d) * 4 + k + 1) * ((double)(k * 16 + l15 + 1) * 0.001);
            e3 += (double)(l15 * 4 + k + 1) * ((double)(k * 16 + q + 4 * d + 1) * 0.001);
        }
        ok0 &= fabs(acc[d] - e0) < 1e-9;
        ok1 &= fabs(acc[d] - e1) < 1e-9;
        ok2 &= fabs(acc[d] - e2) < 1e-9;
        ok3 &= fabs(acc[d] - e3) < 1e-9;
    }
    int f = __all(ok0) ? 0 : (__all(ok1) ? 1 : (__all(ok2) ? 2 : (__all(ok3) ? 3 : 4)));
    if (lane == 0) *flag = f;
}

// ---- phase 1a: implicit-GEMM conv via fp64 MFMA (runs iff layout known) ----
__global__ __launch_bounds__(256)
void conv_mfma(const float* __restrict__ x, const double* __restrict__ wd,
               double* __restrict__ z, const int* __restrict__ flag) {
    const int lay = *flag;
    if (lay > 3) return;

    __shared__ double xs[XS_N];

    const int tid = threadIdx.x;
    const int lane = tid & 63;
    const int wave = tid >> 6;
    const int l15 = lane & 15;
    const int koff = lane >> 4;
    const int cslice = wave & 1;
    const int pslice = wave >> 1;
    const int hbase = 4 * pslice;

    const int w0 = blockIdx.x * PW;
    const int h0 = blockIdx.y * PH;
    const int cob = (blockIdx.z & 1) * 64;
    const int tb = blockIdx.z >> 1;
    const int co_w = cob + 32 * cslice;

    const float* xb = x + (size_t)tb * (CIN * HH * WW);

    d4 acc[2][4];
#pragma unroll
    for (int i = 0; i < 2; ++i)
#pragma unroll
        for (int j = 0; j < 4; ++j)
            acc[i][j] = (d4)(0.0);

    for (int cc = 0; cc < CIN; cc += CI_CHUNK) {
        __syncthreads();
        for (int idx = tid; idx < XS_N; idx += 256) {
            int cil = idx / XS_ROW;
            int rem = idx - cil * XS_ROW;
            int hr = rem / XS_W2;
            int wr = rem - hr * XS_W2;
            int gh = h0 - 1 + hr;
            int gw = w0 - 1 + wr;
            double val = 0.0;
            if (gh >= 0 && gh < HH && gw >= 0 && gw < WW)
                val = (double)xb[(cc + cil) * (HH * WW) + gh * WW + gw];
            xs[idx] = val;
        }
        __syncthreads();

        double a_cur0, a_cur1, b_cur0, b_cur1, b_cur2, b_cur3;
        double a_nxt0, a_nxt1, b_nxt0, b_nxt1, b_nxt2, b_nxt3;
        {
            int kl = koff;
            int cil = kl / 9;
            int r = kl - cil * 9;
            int kh = r / 3;
            int kw = r - kh * 3;
            const double* ap = wd + (size_t)(cc * 9 + kl) * COUT + co_w + l15;
            a_cur0 = ap[0]; a_cur1 = ap[16];
            const double* bp = xs + cil * XS_ROW + (hbase + kh) * XS_W2 + l15 + kw;
            b_cur0 = bp[0]; b_cur1 = bp[XS_W2]; b_cur2 = bp[2 * XS_W2]; b_cur3 = bp[3 * XS_W2];
        }
        for (int ks = 0; ks < 35; ++ks) {
            {
                int kl = (ks + 1) * 4 + koff;
                int cil = kl / 9;
                int r = kl - cil * 9;
                int kh = r / 3;
                int kw = r - kh * 3;
                const double* ap = wd + (size_t)(cc * 9 + kl) * COUT + co_w + l15;
                a_nxt0 = ap[0]; a_nxt1 = ap[16];
                const double* bp = xs + cil * XS_ROW + (hbase + kh) * XS_W2 + l15 + kw;
                b_nxt0 = bp[0]; b_nxt1 = bp[XS_W2]; b_nxt2 = bp[2 * XS_W2]; b_nxt3 = bp[3 * XS_W2];
            }
            acc[0][0] = __builtin_amdgcn_mfma_f64_16x16x4f64(a_cur0, b_cur0, acc[0][0], 0, 0, 0);
            acc[0][1] = __builtin_amdgcn_mfma_f64_16x16x4f64(a_cur0, b_cur1, acc[0][1], 0, 0, 0);
            acc[0][2] = __builtin_amdgcn_mfma_f64_16x16x4f64(a_cur0, b_cur2, acc[0][2], 0, 0, 0);
            acc[0][3] = __builtin_amdgcn_mfma_f64_16x16x4f64(a_cur0, b_cur3, acc[0][3], 0, 0, 0);
            acc[1][0] = __builtin_amdgcn_mfma_f64_16x16x4f64(a_cur1, b_cur0, acc[1][0], 0, 0, 0);
            acc[1][1] = __builtin_amdgcn_mfma_f64_16x16x4f64(a_cur1, b_cur1, acc[1][1], 0, 0, 0);
            acc[1][2] = __builtin_amdgcn_mfma_f64_16x16x4f64(a_cur1, b_cur2, acc[1][2], 0, 0, 0);
            acc[1][3] = __builtin_amdgcn_mfma_f64_16x16x4f64(a_cur1, b_cur3, acc[1][3], 0, 0, 0);
            a_cur0 = a_nxt0; a_cur1 = a_nxt1;
            b_cur0 = b_nxt0; b_cur1 = b_nxt1; b_cur2 = b_nxt2; b_cur3 = b_nxt3;
        }
        acc[0][0] = __builtin_amdgcn_mfma_f64_16x16x4f64(a_cur0, b_cur0, acc[0][0], 0, 0, 0);
        acc[0][1] = __builtin_amdgcn_mfma_f64_16x16x4f64(a_cur0, b_cur1, acc[0][1], 0, 0, 0);
        acc[0][2] = __builtin_amdgcn_mfma_f64_16x16x4f64(a_cur0, b_cur2, acc[0][2], 0, 0, 0);
        acc[0][3] = __builtin_amdgcn_mfma_f64_16x16x4f64(a_cur0, b_cur3, acc[0][3], 0, 0, 0);
        acc[1][0] = __builtin_amdgcn_mfma_f64_16x16x4f64(a_cur1, b_cur0, acc[1][0], 0, 0, 0);
        acc[1][1] = __builtin_amdgcn_mfma_f64_16x16x4f64(a_cur1, b_cur1, acc[1][1], 0, 0, 0);
        acc[1][2] = __builtin_amdgcn_mfma_f64_16x16x4f64(a_cur1, b_cur2, acc[1][2], 0, 0, 0);
        acc[1][3] = __builtin_amdgcn_mfma_f64_16x16x4f64(a_cur1, b_cur3, acc[1][3], 0, 0, 0);
    }

    // ---- store z with probed D layout ----
    double* zb = z + (size_t)tb * (COUT * HH * WW);
#pragma unroll
    for (int i2 = 0; i2 < 2; ++i2) {
        int cw = co_w + 16 * i2;
#pragma unroll
        for (int jt = 0; jt < 4; ++jt) {
            int h = h0 + hbase + jt;
            d4 a = acc[i2][jt];
            if (lay == 0) {          // D[m=4q+d][n=l15]
#pragma unroll
                for (int d = 0; d < 4; ++d)
                    zb[(size_t)(cw + 4 * koff + d) * (HH * WW) + h * WW + w0 + l15] = a[d];
            } else if (lay == 1) {   // D[m=l15][n=4q+d]
                *(d4*)&zb[(size_t)(cw + l15) * (HH * WW) + h * WW + w0 + 4 * koff] = a;
            } else if (lay == 2) {   // D[m=q+4d][n=l15]
#pragma unroll
                for (int d = 0; d < 4; ++d)
                    zb[(size_t)(cw + koff + 4 * d) * (HH * WW) + h * WW + w0 + l15] = a[d];
            } else {                 // D[m=l15][n=q+4d]
#pragma unroll
                for (int d = 0; d < 4; ++d)
                    zb[(size_t)(cw + l15) * (HH * WW) + h * WW + w0 + koff + 4 * d] = a[d];
            }
        }
    }
}

// ---- phase 1b: trusted vector-fp64 conv (runs iff probe found no layout) ----
#define VTILE_H 4
#define VTILE_W 16
#define VXS_W (VTILE_W + 2)
#define VXS_ROW ((VTILE_H + 2) * VXS_W)    // 108 floats per ci
#define VXS_N (CIN * VXS_ROW)
__global__ __launch_bounds__(256, 2)
void conv_f64(const float* __restrict__ x, const double* __restrict__ wd,
              double* __restrict__ z, const int* __restrict__ flag) {
    if (*flag <= 3) return;
    __shared__ float xs[VXS_N];

    const int tid = threadIdx.x;
    const int pt = tid & 15;
    const int cg = tid >> 4;
    const int w0 = blockIdx.x * VTILE_W;
    const int h0 = blockIdx.y * VTILE_H;
    const int tb = blockIdx.z;
    const int co_base = cg * 8;

    const float* xb = x + (size_t)tb * (CIN * HH * WW);
    for (int idx = tid; idx < VXS_N; idx += 256) {
        int ci = idx / VXS_ROW;
        int rem = idx - ci * VXS_ROW;
        int hh = rem / VXS_W;
        int ww2 = rem - hh * VXS_W;
        int gh = h0 - 1 + hh;
        int gw = w0 - 1 + ww2;
        float val = 0.0f;
        if (gh >= 0 && gh < HH && gw >= 0 && gw < WW)
            val = xb[ci * (HH * WW) + gh * WW + gw];
        xs[idx] = val;
    }
    __syncthreads();

    double acc[32];
#pragma unroll
    for (int i = 0; i < 32; ++i) acc[i] = 0.0;

    for (int ci = 0; ci < CIN; ++ci) {
        const float* xr = xs + ci * VXS_ROW;
        const double* wrow = wd + (size_t)(ci * 9) * COUT + co_base;
#pragma unroll
        for (int kh = 0; kh < 3; ++kh) {
#pragma unroll
            for (int kw = 0; kw < 3; ++kw) {
                const double2* wp = (const double2*)(wrow + (kh * 3 + kw) * COUT);
                double2 w01 = wp[0], w23 = wp[1], w45 = wp[2], w67 = wp[3];
                double wv[8] = {w01.x, w01.y, w23.x, w23.y,
                                w45.x, w45.y, w67.x, w67.y};
                double xv[4];
#pragma unroll
                for (int j = 0; j < 4; ++j)
                    xv[j] = (double)xr[(j + kh) * VXS_W + pt + kw];
#pragma unroll
                for (int i = 0; i < 8; ++i) {
#pragma unroll
                    for (int j = 0; j < 4; ++j)
                        acc[i * 4 + j] = fma(wv[i], xv[j], acc[i * 4 + j]);
                }
            }
        }
    }

    double* zb = z + (size_t)tb * (COUT * HH * WW);
#pragma unroll
    for (int i = 0; i < 8; ++i) {
#pragma unroll
        for (int j = 0; j < 4; ++j)
            zb[(size_t)(co_base + i) * (HH * WW) + (h0 + j) * WW + (w0 + pt)]
                = acc[i * 4 + j];
    }
}

// ---- phase 2: LIF scan over t (memory-bound) ----
__global__ __launch_bounds__(256)
void lif_scan(const double* __restrict__ z, float* __restrict__ out) {
    size_t n = ((size_t)blockIdx.x * 256 + threadIdx.x) * 2;
    double v0 = 0.0, v1 = 0.0;
#pragma unroll
    for (int t = 0; t < TT; ++t) {
        double2 zz = *(const double2*)(z + (size_t)t * NPLANE + n);
        v0 = v0 + (zz.x - v0) * 0.5;
        v1 = v1 + (zz.y - v1) * 0.5;
        bool s0 = (v0 >= 1.0), s1 = (v1 >= 1.0);
        float2 o;
        o.x = s0 ? 1.0f : 0.0f;
        o.y = s1 ? 1.0f : 0.0f;
        *(float2*)(out + (size_t)t * NPLANE + n) = o;
        v0 = s0 ? 0.0 : v0;
        v1 = s1 ? 0.0 : v1;
    }
}

// ---- ultimate fallback: R2 fused kernel, if ws too small ----
__global__ __launch_bounds__(256, 2)
void convlif_f64(const float* __restrict__ x, const float* __restrict__ Wt,
                 float* __restrict__ out) {
    __shared__ double xs[CIN * VXS_ROW];
    const int tid = threadIdx.x;
    const int pt = tid & 15;
    const int cg = tid >> 4;
    const int w0 = blockIdx.x * VTILE_W;
    const int h0 = blockIdx.y * VTILE_H;
    const int b = blockIdx.z;
    const int co_base = cg * 8;
    double v[32];
#pragma unroll
    for (int i = 0; i < 32; ++i) v[i] = 0.0;
    for (int t = 0; t < TT; ++t) {
        __syncthreads();
        const float* xb = x + (size_t)(t * BB + b) * (CIN * HH * WW);
        for (int idx = tid; idx < CIN * VXS_ROW; idx += 256) {
            int ci = idx / VXS_ROW;
            int rem = idx - ci * VXS_ROW;
            int hh = rem / VXS_W;
            int ww2 = rem - hh * VXS_W;
            int gh = h0 - 1 + hh;
            int gw = w0 - 1 + ww2;
            double val = 0.0;
            if (gh >= 0 && gh < HH && gw >= 0 && gw < WW)
                val = (double)xb[ci * (HH * WW) + gh * WW + gw];
            xs[idx] = val;
        }
        __syncthreads();
        double acc[32];
#pragma unroll
        for (int i = 0; i < 32; ++i) acc[i] = 0.0;
        for (int ci = 0; ci < CIN; ++ci) {
            const float* wr = Wt + (size_t)co_base * (CIN * 9) + ci * 9;
            const double* xr = xs + ci * VXS_ROW;
#pragma unroll
            for (int kh = 0; kh < 3; ++kh) {
#pragma unroll
                for (int kw = 0; kw < 3; ++kw) {
                    double wv[8];
#pragma unroll
                    for (int i = 0; i < 8; ++i)
                        wv[i] = (double)wr[i * (CIN * 9) + kh * 3 + kw];
                    double xv[4];
#pragma unroll
                    for (int j = 0; j < 4; ++j)
                        xv[j] = xr[(j + kh) * VXS_W + pt + kw];
#pragma unroll
                    for (int i = 0; i < 8; ++i) {
#pragma unroll
                        for (int j = 0; j < 4; ++j)
                            acc[i * 4 + j] = fma(wv[i], xv[j], acc[i * 4 + j]);
                    }
                }
            }
        }
        float* ob = out + (size_t)(t * BB + b) * (COUT * HH * WW);
#pragma unroll
        for (int i = 0; i < 8; ++i) {
#pragma unroll
            for (int j = 0; j < 4; ++j) {
                int k = i * 4 + j;
                double vv = v[k] + (acc[k] - v[k]) * 0.5;
                bool s = (vv >= 1.0);
                ob[(size_t)(co_base + i) * (HH * WW) + (h0 + j) * WW + (w0 + pt)]
                    = s ? 1.0f : 0.0f;
                v[k] = s ? 0.0 : vv;
            }
        }
    }
}

extern "C" void kernel_launch(void* const* d_in, const int* in_sizes, int n_in,
                              void* d_out, int out_size, void* d_ws, size_t ws_size,
                              hipStream_t stream) {
    const float* x = (const float*)d_in[0];
    const float* Wt = (const float*)d_in[1];
    float* out = (float*)d_out;
    if (ws_size >= WS_NEED) {
        double* wd = (double*)d_ws;
        double* z = (double*)((char*)d_ws + W_BYTES);
        int* flag = (int*)((char*)d_ws + FLAG_OFF);
        mfma_probe<<<1, 64, 0, stream>>>(flag);
        wconv_f64<<<(W_ELEMS + 255) / 256, 256, 0, stream>>>(Wt, wd);
        dim3 mgrid(WW / PW, HH / PH, 2 * TT * BB);
        conv_mfma<<<mgrid, 256, 0, stream>>>(x, wd, z, flag);
        dim3 vgrid(WW / VTILE_W, HH / VTILE_H, TT * BB);
        conv_f64<<<vgrid, 256, 0, stream>>>(x, wd, z, flag);
        lif_scan<<<NPLANE / 2 / 256, 256, 0, stream>>>(z, out);
    } else {
        dim3 grid(WW / VTILE_W, HH / VTILE_H, BB);
        convlif_f64<<<grid, 256, 0, stream>>>(x, Wt, out);
    }
}